// Round 2
// baseline (130.828 us; speedup 1.0000x reference)
//
#include <hip/hip_runtime.h>

typedef __attribute__((ext_vector_type(8))) short bf16x8;
typedef __attribute__((ext_vector_type(4))) float f32x4;

__device__ inline unsigned short f2bf(float f) {
  union { float f; unsigned u; } v; v.f = f;
  unsigned r = v.u + 0x7FFFu + ((v.u >> 16) & 1u);   // round-to-nearest-even
  return (unsigned short)(r >> 16);
}

// One wave (64 lanes) per row of 512 f32: normalize to unit L2 norm, emit bf16 bits.
__global__ __launch_bounds__(256) void normalize_rows_512(
    const float* __restrict__ in, unsigned short* __restrict__ out, int rows) {
  const int w = threadIdx.x >> 6, lane = threadIdx.x & 63;
  const int row = blockIdx.x * 4 + w;
  if (row >= rows) return;
  const float* p = in + (size_t)row * 512 + lane * 8;
  float4 a = *reinterpret_cast<const float4*>(p);
  float4 b = *reinterpret_cast<const float4*>(p + 4);
  float ss = a.x*a.x + a.y*a.y + a.z*a.z + a.w*a.w
           + b.x*b.x + b.y*b.y + b.z*b.z + b.w*b.w;
  #pragma unroll
  for (int off = 32; off; off >>= 1) ss += __shfl_xor(ss, off);
  const float inv = 1.0f / fmaxf(sqrtf(ss), 1e-12f);
  unsigned short o[8];
  o[0]=f2bf(a.x*inv); o[1]=f2bf(a.y*inv); o[2]=f2bf(a.z*inv); o[3]=f2bf(a.w*inv);
  o[4]=f2bf(b.x*inv); o[5]=f2bf(b.y*inv); o[6]=f2bf(b.z*inv); o[7]=f2bf(b.w*inv);
  *reinterpret_cast<uint4*>(out + (size_t)row * 512 + lane * 8) =
      *reinterpret_cast<uint4*>(o);
}

// logits[8192,4096] = (1+2l)*(Xn.WnT) - 2l, f16 out. m97 structure:
// 128x128 tile, BK=64, linear LDS, global_load_lds width-16 staging.
#define BM 128
#define BN 128
#define BK 64

__global__ __launch_bounds__(256) void gemm_logits_f16(
    const unsigned short* __restrict__ Xb, const unsigned short* __restrict__ Wb,
    const float* __restrict__ lambd, unsigned short* __restrict__ out16) {
  __shared__ unsigned short As[BM * BK];   // 16 KB, linear [row][k]
  __shared__ unsigned short Bs[BN * BK];   // 16 KB
  const int tid = threadIdx.x, lane = tid & 63, wid = tid >> 6;
  const int wm = wid >> 1, wn = wid & 1;      // 2x2 wave grid, 64x64 each
  const int lrow = lane & 15, kg = lane >> 4;

  // bijective XCD swizzle: nwg=2048, 256 per XCD chunk
  const int id = (int)blockIdx.x;
  const int swz = (id & 7) * 256 + (id >> 3);
  const int bx = swz & 31;                 // 4096/128 = 32 col tiles
  const int by = swz >> 5;                 // 64 row tiles
  const int bm0 = by * BM, bn0 = bx * BN;

  f32x4 acc[4][4];
  #pragma unroll
  for (int m = 0; m < 4; ++m)
    #pragma unroll
    for (int n = 0; n < 4; ++n) { f32x4 z = {0.f,0.f,0.f,0.f}; acc[m][n] = z; }

  // staging geometry: tile = 16 chunks of 1 KB (64 lanes x 16 B); wave w owns 4.
  // chunk c covers rows c*8 + lane/8, k-bytes (lane%8)*16 -> linear LDS.
  const int crow = lane >> 3;
  const int ckel = (lane & 7) * 8;   // k offset in elems

  for (int ko = 0; ko < 512; ko += BK) {
    #pragma unroll
    for (int i = 0; i < 4; ++i) {
      const int c = wid * 4 + i;
      const unsigned short* sa = Xb + (size_t)(bm0 + c*8 + crow) * 512 + ko + ckel;
      const unsigned short* sb = Wb + (size_t)(bn0 + c*8 + crow) * 512 + ko + ckel;
      __builtin_amdgcn_global_load_lds(
          (const __attribute__((address_space(1))) void*)sa,
          (__attribute__((address_space(3))) void*)&As[c * 512], 16, 0, 0);
      __builtin_amdgcn_global_load_lds(
          (const __attribute__((address_space(1))) void*)sb,
          (__attribute__((address_space(3))) void*)&Bs[c * 512], 16, 0, 0);
    }
    __syncthreads();
    #pragma unroll
    for (int kk = 0; kk < 2; ++kk) {
      bf16x8 af[4], bf[4];
      #pragma unroll
      for (int m = 0; m < 4; ++m)
        af[m] = *reinterpret_cast<const bf16x8*>(&As[(wm*64 + m*16 + lrow)*BK + kk*32 + kg*8]);
      #pragma unroll
      for (int n = 0; n < 4; ++n)
        bf[n] = *reinterpret_cast<const bf16x8*>(&Bs[(wn*64 + n*16 + lrow)*BK + kk*32 + kg*8]);
      #pragma unroll
      for (int m = 0; m < 4; ++m)
        #pragma unroll
        for (int n = 0; n < 4; ++n)
          acc[m][n] = __builtin_amdgcn_mfma_f32_16x16x32_bf16(af[m], bf[n], acc[m][n], 0, 0, 0);
    }
    __syncthreads();
  }

  const float lam = lambd[0];
  const float sa_ = 1.0f + 2.0f * lam, sb_ = 2.0f * lam;
  #pragma unroll
  for (int m = 0; m < 4; ++m) {
    #pragma unroll
    for (int n = 0; n < 4; ++n) {
      const int gc = bn0 + wn*64 + n*16 + lrow;
      #pragma unroll
      for (int r = 0; r < 4; ++r) {
        const int gr = bm0 + wm*64 + m*16 + kg*4 + r;  // C/D: col=lane&15, row=(lane>>4)*4+r
        union { _Float16 h; unsigned short u; } cv;
        cv.h = (_Float16)(sa_ * acc[m][n][r] - sb_);
        out16[(size_t)gr * 4096 + gc] = cv.u;
      }
    }
  }
}

// Sparsemax per row of 4096: f16 logits in, f32 out. Exact simplex projection (Michelot).
__global__ __launch_bounds__(256) void sparsemax_f16(
    const unsigned short* __restrict__ zin, float* __restrict__ out) {
  const int tid = threadIdx.x;
  const unsigned short* zr = zin + (size_t)blockIdx.x * 4096;
  float* orow = out + (size_t)blockIdx.x * 4096;

  float v[16];
  #pragma unroll
  for (int b = 0; b < 2; ++b) {
    uint4 pk = *reinterpret_cast<const uint4*>(&zr[b * 2048 + tid * 8]);
    const unsigned short* ph = reinterpret_cast<const unsigned short*>(&pk);
    #pragma unroll
    for (int j = 0; j < 8; ++j) {
      union { unsigned short u; _Float16 h; } cv; cv.u = ph[j];
      v[b * 8 + j] = (float)cv.h;
    }
  }

  __shared__ float sred[4];
  __shared__ int   cred[4];
  const int lane = tid & 63, w = tid >> 6;

  float ls = 0.f;
  #pragma unroll
  for (int j = 0; j < 16; ++j) ls += v[j];
  #pragma unroll
  for (int off = 32; off; off >>= 1) ls += __shfl_xor(ls, off);
  if (lane == 0) sred[w] = ls;
  __syncthreads();
  float tau = (sred[0] + sred[1] + sred[2] + sred[3] - 1.0f) * (1.0f / 4096.0f);
  int prevC = 4096;

  for (int it = 0; it < 32; ++it) {
    __syncthreads();   // protect sred/cred reuse
    float s = 0.f; int c = 0;
    #pragma unroll
    for (int j = 0; j < 16; ++j) { if (v[j] > tau) { s += v[j]; ++c; } }
    #pragma unroll
    for (int off = 32; off; off >>= 1) { s += __shfl_xor(s, off); c += __shfl_xor(c, off); }
    if (lane == 0) { sred[w] = s; cred[w] = c; }
    __syncthreads();
    const float S = sred[0] + sred[1] + sred[2] + sred[3];
    const int   C = cred[0] + cred[1] + cred[2] + cred[3];
    tau = (S - 1.0f) / (float)C;      // nested supports: equal count => converged
    if (C == prevC) break;
    prevC = C;
  }

  #pragma unroll
  for (int b = 0; b < 2; ++b) {
    float4 t0, t1;
    t0.x = fmaxf(v[b*8+0] - tau, 0.f);
    t0.y = fmaxf(v[b*8+1] - tau, 0.f);
    t0.z = fmaxf(v[b*8+2] - tau, 0.f);
    t0.w = fmaxf(v[b*8+3] - tau, 0.f);
    t1.x = fmaxf(v[b*8+4] - tau, 0.f);
    t1.y = fmaxf(v[b*8+5] - tau, 0.f);
    t1.z = fmaxf(v[b*8+6] - tau, 0.f);
    t1.w = fmaxf(v[b*8+7] - tau, 0.f);
    *reinterpret_cast<float4*>(&orow[b * 2048 + tid * 8])     = t0;
    *reinterpret_cast<float4*>(&orow[b * 2048 + tid * 8 + 4]) = t1;
  }
}

extern "C" void kernel_launch(void* const* d_in, const int* in_sizes, int n_in,
                              void* d_out, int out_size, void* d_ws, size_t ws_size,
                              hipStream_t stream) {
  const float* x     = (const float*)d_in[0];   // [8192, 512]
  const float* wgt   = (const float*)d_in[1];   // [4096, 512]
  const float* lambd = (const float*)d_in[2];   // [1]
  float* out = (float*)d_out;                   // [8192, 4096] f32

  unsigned short* xb  = (unsigned short*)d_ws;            // 8192*512 bf16 (8 MB)
  unsigned short* wb  = xb + (size_t)8192 * 512;          // 4096*512 bf16 (4 MB)
  unsigned short* z16 = wb + (size_t)4096 * 512;          // 8192*4096 f16 (64 MB)

  normalize_rows_512<<<8192 / 4, 256, 0, stream>>>(x, xb, 8192);
  normalize_rows_512<<<4096 / 4, 256, 0, stream>>>(wgt, wb, 4096);

  gemm_logits_f16<<<2048, 256, 0, stream>>>(xb, wb, lambd, z16);

  sparsemax_f16<<<8192, 256, 0, stream>>>(z16, out);
}

// Round 3
// 121.485 us; speedup vs baseline: 1.0769x; 1.0769x over previous
//
#include <hip/hip_runtime.h>

typedef __attribute__((ext_vector_type(8))) short bf16x8;
typedef __attribute__((ext_vector_type(4))) float f32x4;

__device__ inline unsigned short f2bf(float f) {
  union { float f; unsigned u; } v; v.f = f;
  unsigned r = v.u + 0x7FFFu + ((v.u >> 16) & 1u);   // round-to-nearest-even
  return (unsigned short)(r >> 16);
}

// One wave (64 lanes) per row of 512 f32: normalize to unit L2 norm, emit bf16 bits.
__global__ __launch_bounds__(256) void normalize_rows_512(
    const float* __restrict__ in, unsigned short* __restrict__ out, int rows) {
  const int w = threadIdx.x >> 6, lane = threadIdx.x & 63;
  const int row = blockIdx.x * 4 + w;
  if (row >= rows) return;
  const float* p = in + (size_t)row * 512 + lane * 8;
  float4 a = *reinterpret_cast<const float4*>(p);
  float4 b = *reinterpret_cast<const float4*>(p + 4);
  float ss = a.x*a.x + a.y*a.y + a.z*a.z + a.w*a.w
           + b.x*b.x + b.y*b.y + b.z*b.z + b.w*b.w;
  #pragma unroll
  for (int off = 32; off; off >>= 1) ss += __shfl_xor(ss, off);
  const float inv = 1.0f / fmaxf(sqrtf(ss), 1e-12f);
  unsigned short o[8];
  o[0]=f2bf(a.x*inv); o[1]=f2bf(a.y*inv); o[2]=f2bf(a.z*inv); o[3]=f2bf(a.w*inv);
  o[4]=f2bf(b.x*inv); o[5]=f2bf(b.y*inv); o[6]=f2bf(b.z*inv); o[7]=f2bf(b.w*inv);
  *reinterpret_cast<uint4*>(out + (size_t)row * 512 + lane * 8) =
      *reinterpret_cast<uint4*>(o);
}

// logits[8192,4096] = (1+2l)*(Xn.WnT) - 2l, f16 out.
// 256x256 tile, BK=64, 8 waves (2Mx4N), 2-phase double-buffered LDS (128 KiB),
// global_load_lds width-16 staging issued before compute (min-2-phase recipe).
#define BM 256
#define BN 256
#define BK 64

#define STAGE(buf_, ko_)                                                          \
  do {                                                                            \
    _Pragma("unroll")                                                             \
    for (int i_ = 0; i_ < 4; ++i_) {                                              \
      const int c_ = wid * 4 + i_;                                                \
      const unsigned short* sa_ = Xb + (size_t)(bm0 + c_*8 + crow) * 512 + (ko_) + ckb; \
      const unsigned short* sb_ = Wb + (size_t)(bn0 + c_*8 + crow) * 512 + (ko_) + ckb; \
      __builtin_amdgcn_global_load_lds(                                           \
          (const __attribute__((address_space(1))) void*)sa_,                     \
          (__attribute__((address_space(3))) void*)&sbuf[buf_][0][c_ * 512], 16, 0, 0); \
      __builtin_amdgcn_global_load_lds(                                           \
          (const __attribute__((address_space(1))) void*)sb_,                     \
          (__attribute__((address_space(3))) void*)&sbuf[buf_][1][c_ * 512], 16, 0, 0); \
    }                                                                             \
  } while (0)

__global__ __launch_bounds__(512, 2) void gemm_logits_f16(
    const unsigned short* __restrict__ Xb, const unsigned short* __restrict__ Wb,
    const float* __restrict__ lambd, unsigned short* __restrict__ out16) {
  __shared__ unsigned short sbuf[2][2][BM * BK];   // [dbuf][A|B][256*64] = 128 KiB
  const int tid = threadIdx.x, lane = tid & 63, wid = tid >> 6;  // 8 waves
  const int wm = wid >> 2, wn = wid & 3;          // 2x4 wave grid, 128x64 each
  const int lrow = lane & 15, kg = lane >> 4;

  // bijective XCD swizzle: 512 blocks, 64 per XCD chunk
  const int id = (int)blockIdx.x;
  const int swz = (id & 7) * 64 + (id >> 3);
  const int bx = swz & 15;                 // 4096/256 = 16 col tiles
  const int by = swz >> 4;                 // 8192/256 = 32 row tiles
  const int bm0 = by * BM, bn0 = bx * BN;

  // staging geometry: each tile (A or B) = 32 chunks of 1 KB (64 lanes x 16 B);
  // wave w owns chunks w*4..w*4+3. chunk c covers rows c*8 + lane/8,
  // k-bytes (lane%8)*16 -> linear LDS (gload_lds writes base + lane*16).
  const int crow = lane >> 3;
  const int ckb  = (lane & 7) * 8;   // k offset in elems

  f32x4 acc[8][4];
  #pragma unroll
  for (int m = 0; m < 8; ++m)
    #pragma unroll
    for (int n = 0; n < 4; ++n) { f32x4 z = {0.f,0.f,0.f,0.f}; acc[m][n] = z; }

  STAGE(0, 0);
  __syncthreads();     // drains vmcnt(0): tile 0 resident

  #pragma unroll
  for (int t = 0; t < 8; ++t) {
    const int cur = t & 1;
    if (t < 7) STAGE(cur ^ 1, (t + 1) * BK);   // issue next tile BEFORE compute
    const unsigned short* Abuf = &sbuf[cur][0][0];
    const unsigned short* Bbuf = &sbuf[cur][1][0];
    #pragma unroll
    for (int ks = 0; ks < 2; ++ks) {
      bf16x8 af[8], bfr[4];
      #pragma unroll
      for (int mf = 0; mf < 8; ++mf)
        af[mf] = *reinterpret_cast<const bf16x8*>(
            &Abuf[(wm*128 + mf*16 + lrow) * BK + ks*32 + kg*8]);
      #pragma unroll
      for (int nf = 0; nf < 4; ++nf)
        bfr[nf] = *reinterpret_cast<const bf16x8*>(
            &Bbuf[(wn*64 + nf*16 + lrow) * BK + ks*32 + kg*8]);
      #pragma unroll
      for (int mf = 0; mf < 8; ++mf)
        #pragma unroll
        for (int nf = 0; nf < 4; ++nf)
          acc[mf][nf] = __builtin_amdgcn_mfma_f32_16x16x32_bf16(
              af[mf], bfr[nf], acc[mf][nf], 0, 0, 0);
    }
    __syncthreads();   // stage landed + all reads of buf[cur] done (WAR-safe)
  }

  const float lam = lambd[0];
  const float sa_ = 1.0f + 2.0f * lam, sb_ = 2.0f * lam;
  #pragma unroll
  for (int mf = 0; mf < 8; ++mf) {
    #pragma unroll
    for (int nf = 0; nf < 4; ++nf) {
      const int gc = bn0 + wn*64 + nf*16 + lrow;
      #pragma unroll
      for (int r = 0; r < 4; ++r) {
        const int gr = bm0 + wm*128 + mf*16 + kg*4 + r;  // C/D: col=lane&15, row=(lane>>4)*4+r
        union { _Float16 h; unsigned short u; } cv;
        cv.h = (_Float16)(sa_ * acc[mf][nf][r] - sb_);
        out16[(size_t)gr * 4096 + gc] = cv.u;
      }
    }
  }
}

// Sparsemax per row of 4096: f16 logits in, f32 out.
// Max-start Michelot: tau_true >= rowmax-1, so U0 = {z > rowmax-1} already
// excludes nearly everything -> ~3-4 iterations instead of ~8-10.
__global__ __launch_bounds__(256) void sparsemax_f16(
    const unsigned short* __restrict__ zin, float* __restrict__ out) {
  const int tid = threadIdx.x;
  const unsigned short* zr = zin + (size_t)blockIdx.x * 4096;
  float* orow = out + (size_t)blockIdx.x * 4096;

  float v[16];
  #pragma unroll
  for (int b = 0; b < 2; ++b) {
    uint4 pk = *reinterpret_cast<const uint4*>(&zr[b * 2048 + tid * 8]);
    const unsigned short* ph = reinterpret_cast<const unsigned short*>(&pk);
    #pragma unroll
    for (int j = 0; j < 8; ++j) {
      union { unsigned short u; _Float16 h; } cv; cv.u = ph[j];
      v[b * 8 + j] = (float)cv.h;
    }
  }

  __shared__ float sred[4];
  __shared__ int   cred[4];
  const int lane = tid & 63, w = tid >> 6;

  // block max
  float mx = v[0];
  #pragma unroll
  for (int j = 1; j < 16; ++j) mx = fmaxf(mx, v[j]);
  #pragma unroll
  for (int off = 32; off; off >>= 1) mx = fmaxf(mx, __shfl_xor(mx, off));
  if (lane == 0) sred[w] = mx;
  __syncthreads();
  const float rowmax = fmaxf(fmaxf(sred[0], sred[1]), fmaxf(sred[2], sred[3]));
  float tau = rowmax - 1.0f;   // valid from-below start: tau_true >= rowmax - 1
  int prevC = -1;

  for (int it = 0; it < 32; ++it) {
    __syncthreads();   // protect sred/cred reuse
    float s = 0.f; int c = 0;
    #pragma unroll
    for (int j = 0; j < 16; ++j) { if (v[j] > tau) { s += v[j]; ++c; } }
    #pragma unroll
    for (int off = 32; off; off >>= 1) { s += __shfl_xor(s, off); c += __shfl_xor(c, off); }
    if (lane == 0) { sred[w] = s; cred[w] = c; }
    __syncthreads();
    const float S = sred[0] + sred[1] + sred[2] + sred[3];
    const int   C = cred[0] + cred[1] + cred[2] + cred[3];
    tau = (S - 1.0f) / (float)C;      // nested supports: equal count => converged
    if (C == prevC) break;
    prevC = C;
  }

  #pragma unroll
  for (int b = 0; b < 2; ++b) {
    float4 t0, t1;
    t0.x = fmaxf(v[b*8+0] - tau, 0.f);
    t0.y = fmaxf(v[b*8+1] - tau, 0.f);
    t0.z = fmaxf(v[b*8+2] - tau, 0.f);
    t0.w = fmaxf(v[b*8+3] - tau, 0.f);
    t1.x = fmaxf(v[b*8+4] - tau, 0.f);
    t1.y = fmaxf(v[b*8+5] - tau, 0.f);
    t1.z = fmaxf(v[b*8+6] - tau, 0.f);
    t1.w = fmaxf(v[b*8+7] - tau, 0.f);
    *reinterpret_cast<float4*>(&orow[b * 2048 + tid * 8])     = t0;
    *reinterpret_cast<float4*>(&orow[b * 2048 + tid * 8 + 4]) = t1;
  }
}

extern "C" void kernel_launch(void* const* d_in, const int* in_sizes, int n_in,
                              void* d_out, int out_size, void* d_ws, size_t ws_size,
                              hipStream_t stream) {
  const float* x     = (const float*)d_in[0];   // [8192, 512]
  const float* wgt   = (const float*)d_in[1];   // [4096, 512]
  const float* lambd = (const float*)d_in[2];   // [1]
  float* out = (float*)d_out;                   // [8192, 4096] f32

  unsigned short* xb  = (unsigned short*)d_ws;            // 8192*512 bf16 (8 MB)
  unsigned short* wb  = xb + (size_t)8192 * 512;          // 4096*512 bf16 (4 MB)
  unsigned short* z16 = wb + (size_t)4096 * 512;          // 8192*4096 f16 (64 MB)

  normalize_rows_512<<<8192 / 4, 256, 0, stream>>>(x, xb, 8192);
  normalize_rows_512<<<4096 / 4, 256, 0, stream>>>(wgt, wb, 4096);

  gemm_logits_f16<<<512, 512, 0, stream>>>(xb, wb, lambd, z16);

  sparsemax_f16<<<8192, 256, 0, stream>>>(z16, out);
}

// Round 4
// 121.148 us; speedup vs baseline: 1.0799x; 1.0028x over previous
//
#include <hip/hip_runtime.h>

typedef __attribute__((ext_vector_type(8))) short bf16x8;
typedef __attribute__((ext_vector_type(4))) float f32x4;

__device__ inline unsigned short f2bf(float f) {
  union { float f; unsigned u; } v; v.f = f;
  unsigned r = v.u + 0x7FFFu + ((v.u >> 16) & 1u);   // round-to-nearest-even
  return (unsigned short)(r >> 16);
}

// One wave (64 lanes) per row of 512 f32: normalize to unit L2 norm, emit bf16 bits.
__global__ __launch_bounds__(256) void normalize_rows_512(
    const float* __restrict__ in, unsigned short* __restrict__ out, int rows) {
  const int w = threadIdx.x >> 6, lane = threadIdx.x & 63;
  const int row = blockIdx.x * 4 + w;
  if (row >= rows) return;
  const float* p = in + (size_t)row * 512 + lane * 8;
  float4 a = *reinterpret_cast<const float4*>(p);
  float4 b = *reinterpret_cast<const float4*>(p + 4);
  float ss = a.x*a.x + a.y*a.y + a.z*a.z + a.w*a.w
           + b.x*b.x + b.y*b.y + b.z*b.z + b.w*b.w;
  #pragma unroll
  for (int off = 32; off; off >>= 1) ss += __shfl_xor(ss, off);
  const float inv = 1.0f / fmaxf(sqrtf(ss), 1e-12f);
  unsigned short o[8];
  o[0]=f2bf(a.x*inv); o[1]=f2bf(a.y*inv); o[2]=f2bf(a.z*inv); o[3]=f2bf(a.w*inv);
  o[4]=f2bf(b.x*inv); o[5]=f2bf(b.y*inv); o[6]=f2bf(b.z*inv); o[7]=f2bf(b.w*inv);
  *reinterpret_cast<uint4*>(out + (size_t)row * 512 + lane * 8) =
      *reinterpret_cast<uint4*>(o);
}

// logits[8192,4096] = (1+2l)*(Xn.WnT) - 2l, f16 out.
// 256x256 tile, BK=64, 8 waves (2Mx4N), 2-phase double-buffered LDS (128 KiB),
// global_load_lds width-16 staging issued before compute (min-2-phase recipe).
#define BM 256
#define BN 256
#define BK 64

#define STAGE(buf_, ko_)                                                          \
  do {                                                                            \
    _Pragma("unroll")                                                             \
    for (int i_ = 0; i_ < 4; ++i_) {                                              \
      const int c_ = wid * 4 + i_;                                                \
      const unsigned short* sa_ = Xb + (size_t)(bm0 + c_*8 + crow) * 512 + (ko_) + ckb; \
      const unsigned short* sb_ = Wb + (size_t)(bn0 + c_*8 + crow) * 512 + (ko_) + ckb; \
      __builtin_amdgcn_global_load_lds(                                           \
          (const __attribute__((address_space(1))) void*)sa_,                     \
          (__attribute__((address_space(3))) void*)&sbuf[buf_][0][c_ * 512], 16, 0, 0); \
      __builtin_amdgcn_global_load_lds(                                           \
          (const __attribute__((address_space(1))) void*)sb_,                     \
          (__attribute__((address_space(3))) void*)&sbuf[buf_][1][c_ * 512], 16, 0, 0); \
    }                                                                             \
  } while (0)

__global__ __launch_bounds__(512, 2) void gemm_logits_f16(
    const unsigned short* __restrict__ Xb, const unsigned short* __restrict__ Wb,
    const float* __restrict__ lambd, unsigned short* __restrict__ out16) {
  __shared__ unsigned short sbuf[2][2][BM * BK];   // [dbuf][A|B][256*64] = 128 KiB
  const int tid = threadIdx.x, lane = tid & 63, wid = tid >> 6;  // 8 waves
  const int wm = wid >> 2, wn = wid & 3;          // 2x4 wave grid, 128x64 each
  const int lrow = lane & 15, kg = lane >> 4;

  // bijective XCD swizzle: 512 blocks, 64 per XCD chunk
  const int id = (int)blockIdx.x;
  const int swz = (id & 7) * 64 + (id >> 3);
  const int bx = swz & 15;                 // 4096/256 = 16 col tiles
  const int by = swz >> 4;                 // 8192/256 = 32 row tiles
  const int bm0 = by * BM, bn0 = bx * BN;

  // staging geometry: each tile (A or B) = 32 chunks of 1 KB (64 lanes x 16 B);
  // wave w owns chunks w*4..w*4+3. chunk c covers rows c*8 + lane/8,
  // k-bytes (lane%8)*16 -> linear LDS (gload_lds writes base + lane*16).
  const int crow = lane >> 3;
  const int ckb  = (lane & 7) * 8;   // k offset in elems

  f32x4 acc[8][4];
  #pragma unroll
  for (int m = 0; m < 8; ++m)
    #pragma unroll
    for (int n = 0; n < 4; ++n) { f32x4 z = {0.f,0.f,0.f,0.f}; acc[m][n] = z; }

  STAGE(0, 0);
  __syncthreads();     // drains vmcnt(0): tile 0 resident

  #pragma unroll
  for (int t = 0; t < 8; ++t) {
    const int cur = t & 1;
    if (t < 7) STAGE(cur ^ 1, (t + 1) * BK);   // issue next tile BEFORE compute
    const unsigned short* Abuf = &sbuf[cur][0][0];
    const unsigned short* Bbuf = &sbuf[cur][1][0];
    #pragma unroll
    for (int ks = 0; ks < 2; ++ks) {
      bf16x8 af[8], bfr[4];
      #pragma unroll
      for (int mf = 0; mf < 8; ++mf)
        af[mf] = *reinterpret_cast<const bf16x8*>(
            &Abuf[(wm*128 + mf*16 + lrow) * BK + ks*32 + kg*8]);
      #pragma unroll
      for (int nf = 0; nf < 4; ++nf)
        bfr[nf] = *reinterpret_cast<const bf16x8*>(
            &Bbuf[(wn*64 + nf*16 + lrow) * BK + ks*32 + kg*8]);
      #pragma unroll
      for (int mf = 0; mf < 8; ++mf)
        #pragma unroll
        for (int nf = 0; nf < 4; ++nf)
          acc[mf][nf] = __builtin_amdgcn_mfma_f32_16x16x32_bf16(
              af[mf], bfr[nf], acc[mf][nf], 0, 0, 0);
    }
    __syncthreads();   // stage landed + all reads of buf[cur] done (WAR-safe)
  }

  const float lam = lambd[0];
  const float sa_ = 1.0f + 2.0f * lam, sb_ = 2.0f * lam;
  #pragma unroll
  for (int mf = 0; mf < 8; ++mf) {
    #pragma unroll
    for (int nf = 0; nf < 4; ++nf) {
      const int gc = bn0 + wn*64 + nf*16 + lrow;
      #pragma unroll
      for (int r = 0; r < 4; ++r) {
        const int gr = bm0 + wm*128 + mf*16 + kg*4 + r;  // C/D: col=lane&15, row=(lane>>4)*4+r
        union { _Float16 h; unsigned short u; } cv;
        cv.h = (_Float16)(sa_ * acc[mf][nf][r] - sb_);
        out16[(size_t)gr * 4096 + gc] = cv.u;
      }
    }
  }
}

// Sparsemax per row of 4096: f16 logits in, f32 out.
// Max-start Michelot: tau_true >= rowmax-1, so U0 = {z > rowmax-1} already
// excludes nearly everything -> ~3-4 iterations instead of ~8-10.
__global__ __launch_bounds__(256) void sparsemax_f16(
    const unsigned short* __restrict__ zin, float* __restrict__ out) {
  const int tid = threadIdx.x;
  const unsigned short* zr = zin + (size_t)blockIdx.x * 4096;
  float* orow = out + (size_t)blockIdx.x * 4096;

  float v[16];
  #pragma unroll
  for (int b = 0; b < 2; ++b) {
    uint4 pk = *reinterpret_cast<const uint4*>(&zr[b * 2048 + tid * 8]);
    const unsigned short* ph = reinterpret_cast<const unsigned short*>(&pk);
    #pragma unroll
    for (int j = 0; j < 8; ++j) {
      union { unsigned short u; _Float16 h; } cv; cv.u = ph[j];
      v[b * 8 + j] = (float)cv.h;
    }
  }

  __shared__ float sred[4];
  __shared__ int   cred[4];
  const int lane = tid & 63, w = tid >> 6;

  // block max
  float mx = v[0];
  #pragma unroll
  for (int j = 1; j < 16; ++j) mx = fmaxf(mx, v[j]);
  #pragma unroll
  for (int off = 32; off; off >>= 1) mx = fmaxf(mx, __shfl_xor(mx, off));
  if (lane == 0) sred[w] = mx;
  __syncthreads();
  const float rowmax = fmaxf(fmaxf(sred[0], sred[1]), fmaxf(sred[2], sred[3]));
  float tau = rowmax - 1.0f;   // valid from-below start: tau_true >= rowmax - 1
  int prevC = -1;

  for (int it = 0; it < 32; ++it) {
    __syncthreads();   // protect sred/cred reuse
    float s = 0.f; int c = 0;
    #pragma unroll
    for (int j = 0; j < 16; ++j) { if (v[j] > tau) { s += v[j]; ++c; } }
    #pragma unroll
    for (int off = 32; off; off >>= 1) { s += __shfl_xor(s, off); c += __shfl_xor(c, off); }
    if (lane == 0) { sred[w] = s; cred[w] = c; }
    __syncthreads();
    const float S = sred[0] + sred[1] + sred[2] + sred[3];
    const int   C = cred[0] + cred[1] + cred[2] + cred[3];
    tau = (S - 1.0f) / (float)C;      // nested supports: equal count => converged
    if (C == prevC) break;
    prevC = C;
  }

  #pragma unroll
  for (int b = 0; b < 2; ++b) {
    float4 t0, t1;
    t0.x = fmaxf(v[b*8+0] - tau, 0.f);
    t0.y = fmaxf(v[b*8+1] - tau, 0.f);
    t0.z = fmaxf(v[b*8+2] - tau, 0.f);
    t0.w = fmaxf(v[b*8+3] - tau, 0.f);
    t1.x = fmaxf(v[b*8+4] - tau, 0.f);
    t1.y = fmaxf(v[b*8+5] - tau, 0.f);
    t1.z = fmaxf(v[b*8+6] - tau, 0.f);
    t1.w = fmaxf(v[b*8+7] - tau, 0.f);
    *reinterpret_cast<float4*>(&orow[b * 2048 + tid * 8])     = t0;
    *reinterpret_cast<float4*>(&orow[b * 2048 + tid * 8 + 4]) = t1;
  }
}

extern "C" void kernel_launch(void* const* d_in, const int* in_sizes, int n_in,
                              void* d_out, int out_size, void* d_ws, size_t ws_size,
                              hipStream_t stream) {
  const float* x     = (const float*)d_in[0];   // [8192, 512]
  const float* wgt   = (const float*)d_in[1];   // [4096, 512]
  const float* lambd = (const float*)d_in[2];   // [1]
  float* out = (float*)d_out;                   // [8192, 4096] f32

  unsigned short* xb  = (unsigned short*)d_ws;            // 8192*512 bf16 (8 MB)
  unsigned short* wb  = xb + (size_t)8192 * 512;          // 4096*512 bf16 (4 MB)
  unsigned short* z16 = wb + (size_t)4096 * 512;          // 8192*4096 f16 (64 MB)

  normalize_rows_512<<<8192 / 4, 256, 0, stream>>>(x, xb, 8192);
  normalize_rows_512<<<4096 / 4, 256, 0, stream>>>(wgt, wb, 4096);

  gemm_logits_f16<<<512, 512, 0, stream>>>(xb, wb, lambd, z16);

  sparsemax_f16<<<8192, 256, 0, stream>>>(z16, out);
}

// Round 5
// 113.178 us; speedup vs baseline: 1.1559x; 1.0704x over previous
//
#include <hip/hip_runtime.h>

typedef __attribute__((ext_vector_type(8))) short bf16x8;
typedef __attribute__((ext_vector_type(4))) float f32x4;

__device__ inline unsigned short f2bf(float f) {
  union { float f; unsigned u; } v; v.f = f;
  unsigned r = v.u + 0x7FFFu + ((v.u >> 16) & 1u);   // round-to-nearest-even
  return (unsigned short)(r >> 16);
}

// One wave (64 lanes) per row of 512 f32: normalize to unit L2 norm, emit bf16 bits.
__global__ __launch_bounds__(256) void normalize_rows_512(
    const float* __restrict__ in, unsigned short* __restrict__ out, int rows) {
  const int w = threadIdx.x >> 6, lane = threadIdx.x & 63;
  const int row = blockIdx.x * 4 + w;
  if (row >= rows) return;
  const float* p = in + (size_t)row * 512 + lane * 8;
  float4 a = *reinterpret_cast<const float4*>(p);
  float4 b = *reinterpret_cast<const float4*>(p + 4);
  float ss = a.x*a.x + a.y*a.y + a.z*a.z + a.w*a.w
           + b.x*b.x + b.y*b.y + b.z*b.z + b.w*b.w;
  #pragma unroll
  for (int off = 32; off; off >>= 1) ss += __shfl_xor(ss, off);
  const float inv = 1.0f / fmaxf(sqrtf(ss), 1e-12f);
  unsigned short o[8];
  o[0]=f2bf(a.x*inv); o[1]=f2bf(a.y*inv); o[2]=f2bf(a.z*inv); o[3]=f2bf(a.w*inv);
  o[4]=f2bf(b.x*inv); o[5]=f2bf(b.y*inv); o[6]=f2bf(b.z*inv); o[7]=f2bf(b.w*inv);
  *reinterpret_cast<uint4*>(out + (size_t)row * 512 + lane * 8) =
      *reinterpret_cast<uint4*>(o);
}

// logits[8192,4096] = (1+2l)*(Xn.WnT) - 2l, f16 out.
// 256x256 tile, BK=32, 8 waves (2Mx4N), TRIPLE-buffered LDS (96 KiB),
// counted-vmcnt pipeline: prefetch distance 2 tiles, boundary wait vmcnt(4)
// (never drain to 0 in main loop), raw s_barrier, 2 phases/tile.
#define BM 256
#define BN 256
#define BK 32

// Stage one 1-KiB chunk (16 rows x 64 B) of A or B for tile at k-offset ko_
// into LDS slot slot_. gload_lds writes base + lane*16 linearly; source is
// per-lane: row c*16 + lane/4, k-elems (lane&3)*8.
#define STAGE_A(slot_, ko_, j_)                                                   \
  do {                                                                            \
    const int c_ = wid * 2 + (j_);                                                \
    const unsigned short* s_ = Xb + (size_t)(bm0 + c_ * 16 + srow) * 512 + (ko_) + skel; \
    __builtin_amdgcn_global_load_lds(                                             \
        (const __attribute__((address_space(1))) void*)s_,                        \
        (__attribute__((address_space(3))) void*)&As[slot_][c_ * 512], 16, 0, 0); \
  } while (0)
#define STAGE_B(slot_, ko_, j_)                                                   \
  do {                                                                            \
    const int c_ = wid * 2 + (j_);                                                \
    const unsigned short* s_ = Wb + (size_t)(bn0 + c_ * 16 + srow) * 512 + (ko_) + skel; \
    __builtin_amdgcn_global_load_lds(                                             \
        (const __attribute__((address_space(1))) void*)s_,                        \
        (__attribute__((address_space(3))) void*)&Bs[slot_][c_ * 512], 16, 0, 0); \
  } while (0)

__global__ __launch_bounds__(512, 2) void gemm_logits_f16(
    const unsigned short* __restrict__ Xb, const unsigned short* __restrict__ Wb,
    const float* __restrict__ lambd, unsigned short* __restrict__ out16) {
  __shared__ unsigned short As[3][BM * BK];   // 3 x 16 KiB
  __shared__ unsigned short Bs[3][BN * BK];   // 3 x 16 KiB
  const int tid = threadIdx.x, lane = tid & 63, wid = tid >> 6;  // 8 waves
  const int wm = wid >> 2, wn = wid & 3;          // 2x4 wave grid, 128x64 each
  const int lrow = lane & 15, kg = lane >> 4;

  // bijective XCD swizzle: 512 blocks, 64 per XCD chunk
  const int id = (int)blockIdx.x;
  const int swz = (id & 7) * 64 + (id >> 3);
  const int bx = swz & 15;                 // 4096/256 = 16 col tiles
  const int by = swz >> 4;                 // 8192/256 = 32 row tiles
  const int bm0 = by * BM, bn0 = bx * BN;

  const int srow = lane >> 2;        // staging: row within 16-row chunk
  const int skel = (lane & 3) * 8;   // staging: k-elem offset

  f32x4 acc[8][4];
  #pragma unroll
  for (int m = 0; m < 8; ++m)
    #pragma unroll
    for (int n = 0; n < 4; ++n) { f32x4 z = {0.f,0.f,0.f,0.f}; acc[m][n] = z; }

  // prologue: stage tiles 0 and 1
  STAGE_A(0, 0, 0); STAGE_A(0, 0, 1); STAGE_B(0, 0, 0); STAGE_B(0, 0, 1);
  STAGE_A(1, BK, 0); STAGE_A(1, BK, 1); STAGE_B(1, BK, 0); STAGE_B(1, BK, 1);
  asm volatile("s_waitcnt vmcnt(4)" ::: "memory");   // tile 0's 4 (oldest) landed
  __builtin_amdgcn_s_barrier();
  __builtin_amdgcn_sched_barrier(0);

  #pragma unroll
  for (int t = 0; t < 16; ++t) {
    const int cur = t % 3, nx2 = (t + 2) % 3;
    // ---- Phase A: stage A-chunks of t+2; compute mf0-3 x nf0-3 ----
    if (t + 2 < 16) { STAGE_A(nx2, (t + 2) * BK, 0); STAGE_A(nx2, (t + 2) * BK, 1); }
    bf16x8 af0[4], bfr[4];
    #pragma unroll
    for (int mf = 0; mf < 4; ++mf)
      af0[mf] = *reinterpret_cast<const bf16x8*>(
          &As[cur][(wm * 128 + mf * 16 + lrow) * BK + kg * 8]);
    #pragma unroll
    for (int nf = 0; nf < 4; ++nf)
      bfr[nf] = *reinterpret_cast<const bf16x8*>(
          &Bs[cur][(wn * 64 + nf * 16 + lrow) * BK + kg * 8]);
    asm volatile("s_waitcnt lgkmcnt(0)" ::: "memory");
    __builtin_amdgcn_sched_barrier(0);
    __builtin_amdgcn_s_setprio(1);
    #pragma unroll
    for (int mf = 0; mf < 4; ++mf)
      #pragma unroll
      for (int nf = 0; nf < 4; ++nf)
        acc[mf][nf] = __builtin_amdgcn_mfma_f32_16x16x32_bf16(
            af0[mf], bfr[nf], acc[mf][nf], 0, 0, 0);
    __builtin_amdgcn_s_setprio(0);
    __builtin_amdgcn_sched_barrier(0);
    // ---- Phase B: stage B-chunks of t+2; compute mf4-7 x nf0-3 ----
    if (t + 2 < 16) { STAGE_B(nx2, (t + 2) * BK, 0); STAGE_B(nx2, (t + 2) * BK, 1); }
    bf16x8 af1[4];
    #pragma unroll
    for (int mf = 0; mf < 4; ++mf)
      af1[mf] = *reinterpret_cast<const bf16x8*>(
          &As[cur][(wm * 128 + 64 + mf * 16 + lrow) * BK + kg * 8]);
    asm volatile("s_waitcnt lgkmcnt(0)" ::: "memory");
    __builtin_amdgcn_sched_barrier(0);
    __builtin_amdgcn_s_setprio(1);
    #pragma unroll
    for (int mf = 0; mf < 4; ++mf)
      #pragma unroll
      for (int nf = 0; nf < 4; ++nf)
        acc[mf + 4][nf] = __builtin_amdgcn_mfma_f32_16x16x32_bf16(
            af1[mf], bfr[nf], acc[mf + 4][nf], 0, 0, 0);
    __builtin_amdgcn_s_setprio(0);
    __builtin_amdgcn_sched_barrier(0);
    // ---- tile boundary: ensure tile t+1 resident, keep t+2's loads in flight
    if (t < 15) {
      if (t < 13) { asm volatile("s_waitcnt vmcnt(4)" ::: "memory"); }
      else        { asm volatile("s_waitcnt vmcnt(0)" ::: "memory"); }
      __builtin_amdgcn_s_barrier();
      __builtin_amdgcn_sched_barrier(0);
    }
  }

  const float lam = lambd[0];
  const float sa_ = 1.0f + 2.0f * lam, sb_ = 2.0f * lam;
  #pragma unroll
  for (int mf = 0; mf < 8; ++mf) {
    #pragma unroll
    for (int nf = 0; nf < 4; ++nf) {
      const int gc = bn0 + wn * 64 + nf * 16 + lrow;
      #pragma unroll
      for (int r = 0; r < 4; ++r) {
        const int gr = bm0 + wm * 128 + mf * 16 + kg * 4 + r;  // C/D: col=lane&15, row=(lane>>4)*4+r
        union { _Float16 h; unsigned short u; } cv;
        cv.h = (_Float16)(sa_ * acc[mf][nf][r] - sb_);
        out16[(size_t)gr * 4096 + gc] = cv.u;
      }
    }
  }
}

// Sparsemax per row of 4096: f16 logits in, f32 out. Michelot from full-set
// start; double-buffered reduce scratch -> ONE barrier per iteration.
__global__ __launch_bounds__(256) void sparsemax_f16(
    const unsigned short* __restrict__ zin, float* __restrict__ out) {
  const int tid = threadIdx.x;
  const unsigned short* zr = zin + (size_t)blockIdx.x * 4096;
  float* orow = out + (size_t)blockIdx.x * 4096;

  float v[16];
  #pragma unroll
  for (int b = 0; b < 2; ++b) {
    uint4 pk = *reinterpret_cast<const uint4*>(&zr[b * 2048 + tid * 8]);
    const unsigned short* ph = reinterpret_cast<const unsigned short*>(&pk);
    #pragma unroll
    for (int j = 0; j < 8; ++j) {
      union { unsigned short u; _Float16 h; } cv; cv.u = ph[j];
      v[b * 8 + j] = (float)cv.h;
    }
  }

  __shared__ float sred[2][4];
  __shared__ int   cred[2][4];
  const int lane = tid & 63, w = tid >> 6;

  // full-set start: tau0 = (sum - 1)/4096
  float ls = 0.f;
  #pragma unroll
  for (int j = 0; j < 16; ++j) ls += v[j];
  #pragma unroll
  for (int off = 32; off; off >>= 1) ls += __shfl_xor(ls, off);
  if (lane == 0) sred[0][w] = ls;
  __syncthreads();
  float tau = (sred[0][0] + sred[0][1] + sred[0][2] + sred[0][3] - 1.0f)
              * (1.0f / 4096.0f);
  int prevC = 4096;

  for (int it = 0; it < 32; ++it) {
    const int pw = 1 - (it & 1);         // alternate scratch slot (WAR-safe, 1 barrier)
    float s = 0.f; int c = 0;
    #pragma unroll
    for (int j = 0; j < 16; ++j) { if (v[j] > tau) { s += v[j]; ++c; } }
    #pragma unroll
    for (int off = 32; off; off >>= 1) { s += __shfl_xor(s, off); c += __shfl_xor(c, off); }
    if (lane == 0) { sred[pw][w] = s; cred[pw][w] = c; }
    __syncthreads();
    const float S = sred[pw][0] + sred[pw][1] + sred[pw][2] + sred[pw][3];
    const int   C = cred[pw][0] + cred[pw][1] + cred[pw][2] + cred[pw][3];
    tau = (S - 1.0f) / (float)C;      // nested supports: equal count => converged
    if (C == prevC) break;
    prevC = C;
  }

  #pragma unroll
  for (int b = 0; b < 2; ++b) {
    float4 t0, t1;
    t0.x = fmaxf(v[b*8+0] - tau, 0.f);
    t0.y = fmaxf(v[b*8+1] - tau, 0.f);
    t0.z = fmaxf(v[b*8+2] - tau, 0.f);
    t0.w = fmaxf(v[b*8+3] - tau, 0.f);
    t1.x = fmaxf(v[b*8+4] - tau, 0.f);
    t1.y = fmaxf(v[b*8+5] - tau, 0.f);
    t1.z = fmaxf(v[b*8+6] - tau, 0.f);
    t1.w = fmaxf(v[b*8+7] - tau, 0.f);
    *reinterpret_cast<float4*>(&orow[b * 2048 + tid * 8])     = t0;
    *reinterpret_cast<float4*>(&orow[b * 2048 + tid * 8 + 4]) = t1;
  }
}

extern "C" void kernel_launch(void* const* d_in, const int* in_sizes, int n_in,
                              void* d_out, int out_size, void* d_ws, size_t ws_size,
                              hipStream_t stream) {
  const float* x     = (const float*)d_in[0];   // [8192, 512]
  const float* wgt   = (const float*)d_in[1];   // [4096, 512]
  const float* lambd = (const float*)d_in[2];   // [1]
  float* out = (float*)d_out;                   // [8192, 4096] f32

  unsigned short* xb  = (unsigned short*)d_ws;            // 8192*512 bf16 (8 MB)
  unsigned short* wb  = xb + (size_t)8192 * 512;          // 4096*512 bf16 (4 MB)
  unsigned short* z16 = wb + (size_t)4096 * 512;          // 8192*4096 f16 (64 MB)

  normalize_rows_512<<<8192 / 4, 256, 0, stream>>>(x, xb, 8192);
  normalize_rows_512<<<4096 / 4, 256, 0, stream>>>(wgt, wb, 4096);

  gemm_logits_f16<<<512, 512, 0, stream>>>(xb, wb, lambd, z16);

  sparsemax_f16<<<8192, 256, 0, stream>>>(z16, out);
}

// Round 6
// 111.667 us; speedup vs baseline: 1.1716x; 1.0135x over previous
//
#include <hip/hip_runtime.h>

typedef __attribute__((ext_vector_type(8))) short bf16x8;
typedef __attribute__((ext_vector_type(4))) float f32x4;

__device__ inline unsigned short f2bf(float f) {
  union { float f; unsigned u; } v; v.f = f;
  unsigned r = v.u + 0x7FFFu + ((v.u >> 16) & 1u);   // round-to-nearest-even
  return (unsigned short)(r >> 16);
}

// One wave per row of 512 f32: normalize to unit L2 norm, emit bf16 bits.
// Rows [0,8192) = x -> xb ; rows [8192, 12288) = weight -> wb.
__global__ __launch_bounds__(256) void normalize_both(
    const float* __restrict__ x, const float* __restrict__ wgt,
    unsigned short* __restrict__ xb, unsigned short* __restrict__ wb) {
  const int w = threadIdx.x >> 6, lane = threadIdx.x & 63;
  const int row = blockIdx.x * 4 + w;
  const float* src;
  unsigned short* dst;
  if (row < 8192) { src = x + (size_t)row * 512;           dst = xb + (size_t)row * 512; }
  else            { src = wgt + (size_t)(row - 8192) * 512; dst = wb + (size_t)(row - 8192) * 512; }
  const float* p = src + lane * 8;
  float4 a = *reinterpret_cast<const float4*>(p);
  float4 b = *reinterpret_cast<const float4*>(p + 4);
  float ss = a.x*a.x + a.y*a.y + a.z*a.z + a.w*a.w
           + b.x*b.x + b.y*b.y + b.z*b.z + b.w*b.w;
  #pragma unroll
  for (int off = 32; off; off >>= 1) ss += __shfl_xor(ss, off);
  const float inv = 1.0f / fmaxf(sqrtf(ss), 1e-12f);
  unsigned short o[8];
  o[0]=f2bf(a.x*inv); o[1]=f2bf(a.y*inv); o[2]=f2bf(a.z*inv); o[3]=f2bf(a.w*inv);
  o[4]=f2bf(b.x*inv); o[5]=f2bf(b.y*inv); o[6]=f2bf(b.z*inv); o[7]=f2bf(b.w*inv);
  *reinterpret_cast<uint4*>(dst + lane * 8) = *reinterpret_cast<uint4*>(o);
}

// logits[8192,4096] = (1+2l)*(Xn.WnT) - 2l, f16 out.
// 256x256 tile, BK=32, 8 waves (2Mx4N), TRIPLE-buffered LDS (96 KiB),
// counted-vmcnt pipeline (prefetch distance 2, boundary wait vmcnt(4)),
// BOTH-SIDES XOR swizzle (rule #21): linear gload_lds dest, source k-quad
// pre-swizzled by kq ^= (row>>1)&3, ds_read applies the same XOR.
// Bank: 16*(row&1) + 4*(kg^((row>>1)&3)) -> 8 lanes tile all bank-groups,
// full wave = 2-way (free) instead of 8-way.
#define BM 256
#define BN 256
#define BK 32

#define STAGE_A(slot_, ko_, j_)                                                   \
  do {                                                                            \
    const int c_ = wid * 2 + (j_);                                                \
    const unsigned short* s_ = Xb + (size_t)(bm0 + c_ * 16 + srow) * 512 + (ko_) + sskel; \
    __builtin_amdgcn_global_load_lds(                                             \
        (const __attribute__((address_space(1))) void*)s_,                        \
        (__attribute__((address_space(3))) void*)&As[slot_][c_ * 512], 16, 0, 0); \
  } while (0)
#define STAGE_B(slot_, ko_, j_)                                                   \
  do {                                                                            \
    const int c_ = wid * 2 + (j_);                                                \
    const unsigned short* s_ = Wb + (size_t)(bn0 + c_ * 16 + srow) * 512 + (ko_) + sskel; \
    __builtin_amdgcn_global_load_lds(                                             \
        (const __attribute__((address_space(1))) void*)s_,                        \
        (__attribute__((address_space(3))) void*)&Bs[slot_][c_ * 512], 16, 0, 0); \
  } while (0)

__global__ __launch_bounds__(512, 2) void gemm_logits_f16(
    const unsigned short* __restrict__ Xb, const unsigned short* __restrict__ Wb,
    const float* __restrict__ lambd, unsigned short* __restrict__ out16) {
  __shared__ unsigned short As[3][BM * BK];   // 3 x 16 KiB
  __shared__ unsigned short Bs[3][BN * BK];   // 3 x 16 KiB
  const int tid = threadIdx.x, lane = tid & 63, wid = tid >> 6;  // 8 waves
  const int wm = wid >> 2, wn = wid & 3;          // 2x4 wave grid, 128x64 each
  const int lrow = lane & 15, kg = lane >> 4;

  // bijective XCD swizzle: 512 blocks, 64 per XCD chunk
  const int id = (int)blockIdx.x;
  const int swz = (id & 7) * 64 + (id >> 3);
  const int bx = swz & 15;                 // 4096/256 = 16 col tiles
  const int by = swz >> 4;                 // 8192/256 = 32 row tiles
  const int bm0 = by * BM, bn0 = bx * BN;

  // staging: chunk c = 16 rows x 64 B; lane l -> row c*16 + l/4, landing at
  // LDS byte c*1024 + l*16 (= logical (row=l>>2, kq=l&3)). Source k-quad is
  // swizzled so slot kq holds logical kq ^ ((row>>1)&3).
  const int srow  = lane >> 2;
  const int sskel = ((lane & 3) ^ ((lane >> 3) & 3)) * 8;   // swizzled k-elem offset

  // reader-side swizzle term: row bits 1-2 come from lrow only
  const int rswz = (lrow >> 1) & 3;
  const int kA = (kg ^ rswz) * 8;     // physical k-quad elem offset for ds_read

  f32x4 acc[8][4];
  #pragma unroll
  for (int m = 0; m < 8; ++m)
    #pragma unroll
    for (int n = 0; n < 4; ++n) { f32x4 z = {0.f,0.f,0.f,0.f}; acc[m][n] = z; }

  // prologue: stage tiles 0 and 1
  STAGE_A(0, 0, 0); STAGE_A(0, 0, 1); STAGE_B(0, 0, 0); STAGE_B(0, 0, 1);
  STAGE_A(1, BK, 0); STAGE_A(1, BK, 1); STAGE_B(1, BK, 0); STAGE_B(1, BK, 1);
  asm volatile("s_waitcnt vmcnt(4)" ::: "memory");   // tile 0's 4 (oldest) landed
  __builtin_amdgcn_s_barrier();
  __builtin_amdgcn_sched_barrier(0);

  #pragma unroll
  for (int t = 0; t < 16; ++t) {
    const int cur = t % 3, nx2 = (t + 2) % 3;
    // ---- Phase A: stage A-chunks of t+2; compute mf0-3 x nf0-3 ----
    if (t + 2 < 16) { STAGE_A(nx2, (t + 2) * BK, 0); STAGE_A(nx2, (t + 2) * BK, 1); }
    bf16x8 af0[4], bfr[4];
    #pragma unroll
    for (int mf = 0; mf < 4; ++mf)
      af0[mf] = *reinterpret_cast<const bf16x8*>(
          &As[cur][(wm * 128 + mf * 16 + lrow) * BK + kA]);
    #pragma unroll
    for (int nf = 0; nf < 4; ++nf)
      bfr[nf] = *reinterpret_cast<const bf16x8*>(
          &Bs[cur][(wn * 64 + nf * 16 + lrow) * BK + kA]);
    asm volatile("s_waitcnt lgkmcnt(0)" ::: "memory");
    __builtin_amdgcn_sched_barrier(0);
    __builtin_amdgcn_s_setprio(1);
    #pragma unroll
    for (int mf = 0; mf < 4; ++mf)
      #pragma unroll
      for (int nf = 0; nf < 4; ++nf)
        acc[mf][nf] = __builtin_amdgcn_mfma_f32_16x16x32_bf16(
            af0[mf], bfr[nf], acc[mf][nf], 0, 0, 0);
    __builtin_amdgcn_s_setprio(0);
    __builtin_amdgcn_sched_barrier(0);
    // ---- Phase B: stage B-chunks of t+2; compute mf4-7 x nf0-3 ----
    if (t + 2 < 16) { STAGE_B(nx2, (t + 2) * BK, 0); STAGE_B(nx2, (t + 2) * BK, 1); }
    bf16x8 af1[4];
    #pragma unroll
    for (int mf = 0; mf < 4; ++mf)
      af1[mf] = *reinterpret_cast<const bf16x8*>(
          &As[cur][(wm * 128 + 64 + mf * 16 + lrow) * BK + kA]);
    asm volatile("s_waitcnt lgkmcnt(0)" ::: "memory");
    __builtin_amdgcn_sched_barrier(0);
    __builtin_amdgcn_s_setprio(1);
    #pragma unroll
    for (int mf = 0; mf < 4; ++mf)
      #pragma unroll
      for (int nf = 0; nf < 4; ++nf)
        acc[mf + 4][nf] = __builtin_amdgcn_mfma_f32_16x16x32_bf16(
            af1[mf], bfr[nf], acc[mf + 4][nf], 0, 0, 0);
    __builtin_amdgcn_s_setprio(0);
    __builtin_amdgcn_sched_barrier(0);
    // ---- tile boundary: ensure tile t+1 resident, keep t+2's loads in flight
    if (t < 15) {
      if (t < 13) { asm volatile("s_waitcnt vmcnt(4)" ::: "memory"); }
      else        { asm volatile("s_waitcnt vmcnt(0)" ::: "memory"); }
      __builtin_amdgcn_s_barrier();
      __builtin_amdgcn_sched_barrier(0);
    }
  }

  const float lam = lambd[0];
  const float sa_ = 1.0f + 2.0f * lam, sb_ = 2.0f * lam;
  #pragma unroll
  for (int mf = 0; mf < 8; ++mf) {
    #pragma unroll
    for (int nf = 0; nf < 4; ++nf) {
      const int gc = bn0 + wn * 64 + nf * 16 + lrow;
      #pragma unroll
      for (int r = 0; r < 4; ++r) {
        const int gr = bm0 + wm * 128 + mf * 16 + kg * 4 + r;  // C/D: col=lane&15, row=(lane>>4)*4+r
        union { _Float16 h; unsigned short u; } cv;
        cv.h = (_Float16)(sa_ * acc[mf][nf][r] - sb_);
        out16[(size_t)gr * 4096 + gc] = cv.u;
      }
    }
  }
}

// Sparsemax per row of 4096: f16 logits in, f32 out. Michelot from full-set
// start; double-buffered reduce scratch -> ONE barrier per iteration.
__global__ __launch_bounds__(256) void sparsemax_f16(
    const unsigned short* __restrict__ zin, float* __restrict__ out) {
  const int tid = threadIdx.x;
  const unsigned short* zr = zin + (size_t)blockIdx.x * 4096;
  float* orow = out + (size_t)blockIdx.x * 4096;

  float v[16];
  #pragma unroll
  for (int b = 0; b < 2; ++b) {
    uint4 pk = *reinterpret_cast<const uint4*>(&zr[b * 2048 + tid * 8]);
    const unsigned short* ph = reinterpret_cast<const unsigned short*>(&pk);
    #pragma unroll
    for (int j = 0; j < 8; ++j) {
      union { unsigned short u; _Float16 h; } cv; cv.u = ph[j];
      v[b * 8 + j] = (float)cv.h;
    }
  }

  __shared__ float sred[2][4];
  __shared__ int   cred[2][4];
  const int lane = tid & 63, w = tid >> 6;

  // full-set start: tau0 = (sum - 1)/4096
  float ls = 0.f;
  #pragma unroll
  for (int j = 0; j < 16; ++j) ls += v[j];
  #pragma unroll
  for (int off = 32; off; off >>= 1) ls += __shfl_xor(ls, off);
  if (lane == 0) sred[0][w] = ls;
  __syncthreads();
  float tau = (sred[0][0] + sred[0][1] + sred[0][2] + sred[0][3] - 1.0f)
              * (1.0f / 4096.0f);
  int prevC = 4096;

  for (int it = 0; it < 32; ++it) {
    const int pw = 1 - (it & 1);         // alternate scratch slot (WAR-safe, 1 barrier)
    float s = 0.f; int c = 0;
    #pragma unroll
    for (int j = 0; j < 16; ++j) { if (v[j] > tau) { s += v[j]; ++c; } }
    #pragma unroll
    for (int off = 32; off; off >>= 1) { s += __shfl_xor(s, off); c += __shfl_xor(c, off); }
    if (lane == 0) { sred[pw][w] = s; cred[pw][w] = c; }
    __syncthreads();
    const float S = sred[pw][0] + sred[pw][1] + sred[pw][2] + sred[pw][3];
    const int   C = cred[pw][0] + cred[pw][1] + cred[pw][2] + cred[pw][3];
    tau = (S - 1.0f) / (float)C;      // nested supports: equal count => converged
    if (C == prevC) break;
    prevC = C;
  }

  #pragma unroll
  for (int b = 0; b < 2; ++b) {
    float4 t0, t1;
    t0.x = fmaxf(v[b*8+0] - tau, 0.f);
    t0.y = fmaxf(v[b*8+1] - tau, 0.f);
    t0.z = fmaxf(v[b*8+2] - tau, 0.f);
    t0.w = fmaxf(v[b*8+3] - tau, 0.f);
    t1.x = fmaxf(v[b*8+4] - tau, 0.f);
    t1.y = fmaxf(v[b*8+5] - tau, 0.f);
    t1.z = fmaxf(v[b*8+6] - tau, 0.f);
    t1.w = fmaxf(v[b*8+7] - tau, 0.f);
    *reinterpret_cast<float4*>(&orow[b * 2048 + tid * 8])     = t0;
    *reinterpret_cast<float4*>(&orow[b * 2048 + tid * 8 + 4]) = t1;
  }
}

extern "C" void kernel_launch(void* const* d_in, const int* in_sizes, int n_in,
                              void* d_out, int out_size, void* d_ws, size_t ws_size,
                              hipStream_t stream) {
  const float* x     = (const float*)d_in[0];   // [8192, 512]
  const float* wgt   = (const float*)d_in[1];   // [4096, 512]
  const float* lambd = (const float*)d_in[2];   // [1]
  float* out = (float*)d_out;                   // [8192, 4096] f32

  unsigned short* xb  = (unsigned short*)d_ws;            // 8192*512 bf16 (8 MB)
  unsigned short* wb  = xb + (size_t)8192 * 512;          // 4096*512 bf16 (4 MB)
  unsigned short* z16 = wb + (size_t)4096 * 512;          // 8192*4096 f16 (64 MB)

  normalize_both<<<(8192 + 4096) / 4, 256, 0, stream>>>(x, wgt, xb, wb);

  gemm_logits_f16<<<512, 512, 0, stream>>>(xb, wb, lambd, z16);

  sparsemax_f16<<<8192, 256, 0, stream>>>(z16, out);
}